// Round 2
// baseline (106017.993 us; speedup 1.0000x reference)
//
#include <hip/hip_runtime.h>
#include <hip/hip_bf16.h>
#include <stdint.h>

#define Hd 512
#define NG 2048      // 4*H
#define MAXN 256
#define NWG 16

__device__ __forceinline__ float sigmf(float x){
  x = fminf(fmaxf(x, -30.f), 30.f);
  return 1.f/(1.f + __expf(-x));
}
__device__ __forceinline__ float tanh_c(float x){
  x = fminf(fmaxf(x, -10.f), 10.f);
  float e = __expf(2.f*x);
  return (e - 1.f)/(e + 1.f);
}

// ---- init: ring tags to "never" ----
__global__ void init_rings(unsigned long long* rn, unsigned long long* re){
  int i = blockIdx.x*256 + threadIdx.x;   // 8*256 = 2048
  if (i < 1024) rn[i] = ~0ull;
  else          re[i-1024] = ~0ull;
}

// ---- init: logits region of d_out gets ep_b (scan atomicAdds partials on top) ----
__global__ void init_logits(float* out, const float* __restrict__ epb, const int* __restrict__ nn){
  int N = *nn;
  long E = (long)N*(N-1)/2;
  long idx = (long)blockIdx.x*256 + threadIdx.x;
  long e = idx >> 2; int q = (int)(idx & 3);
  if (e < E) out[(long)N*Hd + e*4 + q] = epb[q];
}

// ---- C[m][n] = bias0[n]+bias1[n] + sum_k A[m][k]*B[n*ldb+boff+k], K=512 ----
__global__ void gemv_bias(const float* __restrict__ A, int lda,
                          const float* __restrict__ B, int ldb, int boff,
                          const float* __restrict__ b0, const float* __restrict__ b1,
                          float* __restrict__ C, int ldc, int ncols,
                          const int* __restrict__ nn){
  int N = *nn;
  int m = blockIdx.y;
  int n = blockIdx.x*64 + threadIdx.x;
  if (m >= N || n >= ncols) return;
  const float4* a4 = reinterpret_cast<const float4*>(A + (size_t)m*lda);
  const float4* b4 = reinterpret_cast<const float4*>(B + (size_t)n*ldb + boff);
  float s0=0.f, s1=0.f, s2=0.f, s3=0.f;
  #pragma unroll 8
  for (int k=0; k<Hd/4; ++k){
    float4 av = a4[k], bv = b4[k];
    s0 = fmaf(av.x, bv.x, s0);
    s1 = fmaf(av.y, bv.y, s1);
    s2 = fmaf(av.z, bv.z, s2);
    s3 = fmaf(av.w, bv.w, s3);
  }
  float bias = 0.f;
  if (b0) bias += b0[n];
  if (b1) bias += b1[n];
  C[(size_t)m*ldc + n] = (s0+s1)+(s2+s3) + bias;
}

// ---- persistent distributed LSTM scan ----
// 16 WGs x 256 threads. WG w owns hidden units [32w, 32w+32) -> 128 gate rows.
// Thread (r = tid&127, half = tid>>7) holds W_hh[G(r)][half*256 .. +256) in 64 float4 VGPRs.
// Cross-WG h exchange: u64 = (step<<32)|f32bits(h), agent-scope atomics, depth-2 ring.
template<int MODE>   // 0 = node, 1 = edge
__global__ __launch_bounds__(256, 1) void lstm_scan(
    const float* __restrict__ Whh,      // 2048 x 512
    const float* __restrict__ xp,       // node: N x 2048
    const float* __restrict__ P,        // edge: N x 2048 (bias folded)
    const float* __restrict__ Q,        // edge: N x 2048
    const float* __restrict__ epW,      // edge: 4 x 512
    unsigned long long* ring,           // 2 x 512
    float* hs_out,                      // node: N x 512
    float* out_base,                    // edge: d_out (logits at +N*512)
    const int* __restrict__ nn)
{
  const int w   = blockIdx.x;
  const int tid = threadIdx.x;
  const int N   = *nn;
  const int L   = MODE ? (N*(N-1))/2 : N;
  const int r    = tid & 127;
  const int half = tid >> 7;
  const int G = (r>>5)*Hd + w*32 + (r&31);   // global gate row

  float4 wreg[64];
  {
    const float4* wr = reinterpret_cast<const float4*>(Whh + (size_t)G*Hd) + half*64;
    #pragma unroll
    for (int q=0; q<64; ++q) wreg[q] = wr[q];
  }

  __shared__ __align__(16) float hlds[Hd];
  __shared__ float part[256];
  __shared__ float gates[128];

  for (int e=tid; e<Hd; e+=256) hlds[e] = 0.f;

  float c = 0.f;                       // cell state: thread k<32 owns unit 32w+k
  float epv = 0.f;
  if (MODE && tid < 128) epv = epW[(tid>>5)*Hd + w*32 + (tid&31)];
  float* logits = MODE ? (out_base + (size_t)N*Hd) : nullptr;

  int ei = 0, ej = 1;
  __syncthreads();

  for (int t=0; t<L; ++t){
    // xp term for this step (global loads; overlap with matvec below)
    float pq = 0.f;
    if (tid < 128){
      if (MODE) pq = P[(size_t)ei*NG + G] + Q[(size_t)ej*NG + G];
      else      pq = xp[(size_t)t*NG + G];
    }

    // matvec: part[tid] = sum over 256 cols of W[G][.] * h_prev[.]
    {
      const float4* h4 = reinterpret_cast<const float4*>(hlds) + half*64;
      float a0=0.f, a1=0.f, a2=0.f, a3=0.f;
      #pragma unroll
      for (int q=0; q<64; ++q){
        float4 hv = h4[q];                       // same-address broadcast per wave
        a0 = fmaf(wreg[q].x, hv.x, a0);
        a1 = fmaf(wreg[q].y, hv.y, a1);
        a2 = fmaf(wreg[q].z, hv.z, a2);
        a3 = fmaf(wreg[q].w, hv.w, a3);
      }
      part[tid] = (a0+a1)+(a2+a3);
    }
    __syncthreads();
    if (tid < 128) gates[tid] = part[tid] + part[tid+128] + pq;
    __syncthreads();

    if (tid < 32){
      float gi = gates[tid], gf = gates[32+tid], gg = gates[64+tid], go = gates[96+tid];
      float iv = sigmf(gi), fv = sigmf(gf), gv = tanh_c(gg), ov = sigmf(go);
      c = fmaf(fv, c, iv*gv);
      float h = ov * tanh_c(c);
      hlds[w*32 + tid] = h;                      // own slice direct to LDS
      __hip_atomic_store(&ring[(size_t)(t&1)*Hd + w*32 + tid],
          ((unsigned long long)(unsigned)t << 32) | (unsigned long long)__float_as_uint(h),
          __ATOMIC_RELAXED, __HIP_MEMORY_SCOPE_AGENT);
      if (!MODE) hs_out[(size_t)t*Hd + w*32 + tid] = h;
    }

    // gather the other 15 slices (tag-match poll; no fences needed)
    {
      const int e0 = 2*tid, e1 = 2*tid + 1;
      unsigned long long* base = ring + (size_t)(t&1)*Hd;
      bool need0 = (e0>>5) != w;
      bool need1 = (e1>>5) != w;
      const unsigned ut = (unsigned)t;
      while (need0 || need1){
        if (need0){
          unsigned long long v = __hip_atomic_load(base + e0, __ATOMIC_RELAXED, __HIP_MEMORY_SCOPE_AGENT);
          if ((unsigned)(v>>32) == ut){ hlds[e0] = __uint_as_float((unsigned)v); need0 = false; }
        }
        if (need1){
          unsigned long long v = __hip_atomic_load(base + e1, __ATOMIC_RELAXED, __HIP_MEMORY_SCOPE_AGENT);
          if ((unsigned)(v>>32) == ut){ hlds[e1] = __uint_as_float((unsigned)v); need1 = false; }
        }
      }
    }
    __syncthreads();

    // edge logits: partial over own 32 units, shfl-reduce, one atomicAdd per gate-quarter
    if (MODE && tid < 128){
      float v = epv * hlds[w*32 + (tid&31)];
      #pragma unroll
      for (int mlane=16; mlane>=1; mlane>>=1) v += __shfl_xor(v, mlane, 64);
      if ((tid&31) == 0) atomicAdd(&logits[(size_t)t*4 + (tid>>5)], v);
    }

    if (MODE){ ej++; if (ej == N){ ei++; ej = ei+1; } }
  }
}

extern "C" void kernel_launch(void* const* d_in, const int* in_sizes, int n_in,
                              void* d_out, int out_size, void* d_ws, size_t ws_size,
                              hipStream_t stream){
  const int*   nn   = (const int*)  d_in[0];
  const float* emb  = (const float*)d_in[1];
  const float* nWih = (const float*)d_in[2];
  const float* nWhh = (const float*)d_in[3];
  const float* nbih = (const float*)d_in[4];
  const float* nbhh = (const float*)d_in[5];
  const float* eWih = (const float*)d_in[6];   // 2048 x 1024
  const float* eWhh = (const float*)d_in[7];
  const float* ebih = (const float*)d_in[8];
  const float* ebhh = (const float*)d_in[9];
  const float* npW  = (const float*)d_in[10];
  const float* npb  = (const float*)d_in[11];
  const float* epW  = (const float*)d_in[12];
  const float* epb  = (const float*)d_in[13];
  float* out = (float*)d_out;

  // ws layout (floats). xp_n region is reused for P after the node scan consumes it.
  float* ws_f = (float*)d_ws;
  float* xp_n = ws_f;                    // 256*2048 = 524288   (later reused as P)
  float* Pb   = ws_f;                    // alias of xp_n (safe: written after node scan)
  float* Qb   = ws_f + 524288;           // 256*2048
  float* nhs  = ws_f + 1048576;          // 256*512 = 131072
  unsigned long long* ringN = (unsigned long long*)(ws_f + 1179648);  // 1024 u64
  unsigned long long* ringE = ringN + 1024;                            // 1024 u64

  init_rings <<<dim3(8),   dim3(256), 0, stream>>>(ringN, ringE);
  init_logits<<<dim3(510), dim3(256), 0, stream>>>(out, epb, nn);

  // xp_node = emb[:N] @ node_W_ih.T + (b_ih + b_hh)
  gemv_bias<<<dim3(32, MAXN), dim3(64), 0, stream>>>(emb, 512, nWih, 512, 0,
                                                     nbih, nbhh, xp_n, 2048, 2048, nn);
  // node LSTM scan -> nhs
  lstm_scan<0><<<dim3(NWG), dim3(256), 0, stream>>>(nWhh, xp_n, nullptr, nullptr, nullptr,
                                                    ringN, nhs, nullptr, nn);
  // generated_x = nhs @ np_W.T + np_b  -> d_out[0 : N*512]
  gemv_bias<<<dim3(8, MAXN), dim3(64), 0, stream>>>(nhs, 512, npW, 512, 0,
                                                    npb, nullptr, out, 512, 512, nn);
  // P = gx @ W1.T + (edge_b_ih + edge_b_hh);  Q = gx @ W2.T
  gemv_bias<<<dim3(32, MAXN), dim3(64), 0, stream>>>(out, 512, eWih, 1024, 0,
                                                     ebih, ebhh, Pb, 2048, 2048, nn);
  gemv_bias<<<dim3(32, MAXN), dim3(64), 0, stream>>>(out, 512, eWih, 1024, 512,
                                                     nullptr, nullptr, Qb, 2048, 2048, nn);
  // edge LSTM scan + in-scan logits -> d_out[N*512 : ]
  lstm_scan<1><<<dim3(NWG), dim3(256), 0, stream>>>(eWhh, nullptr, Pb, Qb, epW,
                                                    ringE, nullptr, out, nn);
}